// Round 5
// baseline (764.118 us; speedup 1.0000x reference)
//
#include <hip/hip_runtime.h>
#include <hip/hip_bf16.h>

#define NNODES 100000
#define NEDGES 2500000
#define CIN 32
#define CHID 16
#define COUT 64
#define NGRAPH 64

#define NPB 256                 // nodes per bucket
#define NBUCKET 391             // ceil(100000/256)
#define BCAP 7424               // per-bucket capacity: mean 6394, sigma 80 -> ~13 sigma
#define TILE 8192               // edges per binsort block
#define NTB 306                 // ceil(2.5M/8192)

// ---------------- workspace layout (4-byte units) ----------------------------
// gcnt  [0, 512)               int, zeroed (391 used)
// ginv  [512, 576)             f32
// ebuf  [640, 2903424)         int packed (src<<8)|dst_local, 391*7424
// xl    [2903424, 4503424)     f32 N*16
// xr    [4503424, 6103424)     f32 N*16
// h     [6103424, 7703424)     f32 N*16    => 30.8 MB total
#define OFF_GCNT  0
#define OFF_GINV  512
#define OFF_EBUF  640
#define OFF_XL    2903424
#define OFF_XR    4503424
#define OFF_H     6103424

// LDS counting-sort binning: each block sorts 8192 contiguous edges by
// 256-node bucket in LDS, then copies each bucket's run CONTIGUOUSLY to that
// bucket's global region (one space-claim atomic per bucket per block).
// Global writes are sequential full lines -> no partial-line write amp.
__global__ __launch_bounds__(512) void binsort(const int* __restrict__ src,
                                               const int* __restrict__ dst,
                                               int* __restrict__ gcnt,
                                               int* __restrict__ ebuf) {
    __shared__ int hist[NBUCKET];
    __shared__ int binstart[NBUCKET];
    __shared__ int cursor[NBUCKET];
    __shared__ int gbase[NBUCKET];
    __shared__ int tmp[512];
    __shared__ int sbuf[TILE];
    int tid = threadIdx.x;
    int base = blockIdx.x * TILE;
    int cnt = min(NEDGES - base, TILE);
    for (int i = tid; i < NBUCKET; i += 512) hist[i] = 0;
    __syncthreads();
    int v[16], k[16];
#pragma unroll
    for (int j = 0; j < 16; j++) {
        int i = tid + j * 512;
        if (i < cnt) {
            int d = dst[base + i], s = src[base + i];
            k[j] = d >> 8;
            v[j] = (s << 8) | (d & 255);
            atomicAdd(&hist[k[j]], 1);
        }
    }
    __syncthreads();
    int hv = (tid < NBUCKET) ? hist[tid] : 0;
    tmp[tid] = hv;
    __syncthreads();
#pragma unroll
    for (int dd = 1; dd < 512; dd <<= 1) {
        int u = (tid >= dd) ? tmp[tid - dd] : 0;
        __syncthreads();
        tmp[tid] += u;
        __syncthreads();
    }
    if (tid < NBUCKET) {
        int excl = tmp[tid] - hv;
        binstart[tid] = excl;
        cursor[tid] = excl;
        gbase[tid] = (hv > 0) ? atomicAdd(&gcnt[tid], hv) : 0;
    }
    __syncthreads();
#pragma unroll
    for (int j = 0; j < 16; j++) {
        int i = tid + j * 512;
        if (i < cnt) {
            int p = atomicAdd(&cursor[k[j]], 1);
            sbuf[p] = v[j];
        }
    }
    __syncthreads();
    // wave w copies bins w, w+8, ... ; run stores are contiguous
    int wave = tid >> 6, lane = tid & 63;
    for (int b = wave; b < NBUCKET; b += 8) {
        int c2 = hist[b];
        if (c2 == 0) continue;
        int g = gbase[b];
        int gs = min(g, BCAP);
        int ncopy = min(g + c2, BCAP) - gs;    // overflow-guarded (13 sigma)
        int ls = binstart[b];
        int* dp = ebuf + (size_t)b * BCAP + gs;
        for (int i = lane; i < ncopy; i += 64) dp[i] = sbuf[ls + i];
    }
}

__device__ inline int lower_bound_i(const int* __restrict__ b, int n, int key) {
    int lo = 0, hi = n;
    while (lo < hi) {
        int m = (lo + hi) >> 1;
        if (b[m] < key) lo = m + 1; else hi = m;
    }
    return lo;
}

__global__ void graph_inv(const int* __restrict__ batch, float* __restrict__ ginv) {
    int g = threadIdx.x;
    if (g >= NGRAPH) return;
    int s = lower_bound_i(batch, NNODES, g);
    int e = lower_bound_i(batch, NNODES, g + 1);
    ginv[g] = 1.0f / (float)max(e - s, 1);
}

// xl = x @ w1_l.T ; xr = x @ w1_r.T + b1
__global__ __launch_bounds__(256) void transform1(const float* __restrict__ x,
                                                  const float* __restrict__ w1l,
                                                  const float* __restrict__ b1,
                                                  const float* __restrict__ w1r,
                                                  float* __restrict__ xl,
                                                  float* __restrict__ xr) {
    __shared__ float wl[CHID * CIN];
    __shared__ float wr[CHID * CIN];
    __shared__ float bs[CHID];
    for (int i = threadIdx.x; i < CHID * CIN; i += 256) { wl[i] = w1l[i]; wr[i] = w1r[i]; }
    if (threadIdx.x < CHID) bs[threadIdx.x] = b1[threadIdx.x];
    __syncthreads();
    int n = blockIdx.x * 256 + threadIdx.x;
    if (n >= NNODES) return;
    float xv[CIN];
    const float4* x4 = (const float4*)(x + (size_t)n * CIN);
#pragma unroll
    for (int q = 0; q < CIN / 4; q++) {
        float4 v = x4[q];
        xv[4*q] = v.x; xv[4*q+1] = v.y; xv[4*q+2] = v.z; xv[4*q+3] = v.w;
    }
#pragma unroll
    for (int o = 0; o < CHID; o++) {
        float aL = 0.f, aR = bs[o];
#pragma unroll
        for (int i = 0; i < CIN; i++) {
            aL = fmaf(wl[o * CIN + i], xv[i], aL);
            aR = fmaf(wr[o * CIN + i], xv[i], aR);
        }
        xl[(size_t)n * CHID + o] = aL;
        xr[(size_t)n * CHID + o] = aR;
    }
}

// layer-1 aggregate, CSR-free: one block per 256-node bucket, LDS f32
// accumulators + degree hist; 16-lane groups stream the bucket's edge run
// (coalesced 64B row gathers, ds_add_f32 accumulate, <=2-way bank alias=free).
// Finalize: h = relu(acc/deg + xr).
__global__ __launch_bounds__(512) void agg1_direct(const int* __restrict__ gcnt,
                                                   const int* __restrict__ ebuf,
                                                   const float* __restrict__ xl,
                                                   const float* __restrict__ xr,
                                                   float* __restrict__ h) {
    __shared__ float acc[NPB * CHID];
    __shared__ int hist[NPB];
    int b = blockIdx.x, tid = threadIdx.x;
    int nodes0 = b << 8;
    int nloc = min(NPB, NNODES - nodes0);
    int cnt = min(gcnt[b], BCAP);
    for (int i = tid; i < NPB * CHID; i += 512) acc[i] = 0.f;
    for (int i = tid; i < NPB; i += 512) hist[i] = 0;
    __syncthreads();
    const int* run = ebuf + (size_t)b * BCAP;
    int grp = tid >> 4, c = tid & 15;      // 32 groups of 16 lanes
    for (int i = grp; i < cnt; i += 32) {
        int v = run[i];
        int s = v >> 8, dl = v & 255;
        float val = xl[(size_t)s * CHID + c];
        atomicAdd(&acc[dl * CHID + c], val);
        if (c == 0) atomicAdd(&hist[dl], 1);
    }
    __syncthreads();
    for (int idx = tid; idx < nloc * CHID; idx += 512) {
        int dl = idx >> 4;
        float mean = acc[idx] / (float)max(hist[dl], 1);
        size_t gi = (size_t)nodes0 * CHID + idx;
        h[gi] = fmaxf(mean + xr[gi], 0.f);
    }
}

// layer-2 aggregate + output transform + fused graph pooling, CSR-free.
__global__ __launch_bounds__(512) void agg2_pool(const int* __restrict__ gcnt,
                                                 const int* __restrict__ ebuf,
                                                 const float* __restrict__ h,
                                                 const float* __restrict__ w2l,
                                                 const float* __restrict__ b2,
                                                 const float* __restrict__ w2r,
                                                 const int* __restrict__ batch,
                                                 const float* __restrict__ ginv,
                                                 float* __restrict__ out) {
    __shared__ float wlT[CHID * COUT];     // transposed -> conflict-free matmul
    __shared__ float wrT[CHID * COUT];
    __shared__ float bs[COUT];
    __shared__ float acc[NPB * CHID];
    __shared__ int hist[NPB];
    __shared__ float pool[4 * COUT];       // bucket spans <=2 graphs (~1560 nodes/graph)
    __shared__ int used[4];
    int b = blockIdx.x, tid = threadIdx.x;
    int nodes0 = b << 8;
    int nloc = min(NPB, NNODES - nodes0);
    int cnt = min(gcnt[b], BCAP);
    for (int idx = tid; idx < CHID * COUT; idx += 512) {
        int i = idx >> 6, o = idx & 63;
        wlT[idx] = w2l[o * CHID + i];
        wrT[idx] = w2r[o * CHID + i];
    }
    if (tid < COUT) bs[tid] = b2[tid];
    for (int i = tid; i < NPB * CHID; i += 512) acc[i] = 0.f;
    for (int i = tid; i < NPB; i += 512) hist[i] = 0;
    for (int i = tid; i < 4 * COUT; i += 512) pool[i] = 0.f;
    if (tid < 4) used[tid] = 0;
    __syncthreads();
    const int* run = ebuf + (size_t)b * BCAP;
    int grp = tid >> 4, c = tid & 15;
    for (int i = grp; i < cnt; i += 32) {
        int v = run[i];
        int s = v >> 8, dl = v & 255;
        float val = h[(size_t)s * CHID + c];
        atomicAdd(&acc[dl * CHID + c], val);
        if (c == 0) atomicAdd(&hist[dl], 1);
    }
    __syncthreads();
    int gbase = batch[nodes0];
    int nl0 = tid >> 4;                    // 0..31
#pragma unroll 1
    for (int it = 0; it < 8; it++) {
        int dl = it * 32 + nl0;
        if (dl >= nloc) continue;
        int node = nodes0 + dl;
        float inv = 1.0f / (float)max(hist[dl], 1);
        int gid = batch[node];
        int gloc = min(gid - gbase, 3);
        float gw = ginv[gid];
        if (c == 0) used[gloc] = 1;
        float m[CHID], hv[CHID];
        const float4* h4 = (const float4*)(h + (size_t)node * CHID);
#pragma unroll
        for (int q = 0; q < CHID / 4; q++) {
            float4 vv = h4[q];
            hv[4*q] = vv.x; hv[4*q+1] = vv.y; hv[4*q+2] = vv.z; hv[4*q+3] = vv.w;
        }
#pragma unroll
        for (int i = 0; i < CHID; i++) m[i] = acc[dl * CHID + i] * inv;
#pragma unroll
        for (int kk = 0; kk < 4; kk++) {
            int o = c + 16 * kk;
            float s = bs[o];
#pragma unroll
            for (int i = 0; i < CHID; i++) {
                s = fmaf(wlT[i * COUT + o], m[i], s);
                s = fmaf(wrT[i * COUT + o], hv[i], s);
            }
            atomicAdd(&pool[gloc * COUT + o], s * gw);
        }
    }
    __syncthreads();
    for (int idx = tid; idx < 4 * COUT; idx += 512) {
        int row = idx >> 6;
        if (used[row]) atomicAdd(&out[(gbase + row) * COUT + (idx & 63)], pool[idx]);
    }
}

extern "C" void kernel_launch(void* const* d_in, const int* in_sizes, int n_in,
                              void* d_out, int out_size, void* d_ws, size_t ws_size,
                              hipStream_t stream) {
    const float* x    = (const float*)d_in[0];
    const int*   ei   = (const int*)d_in[1];   // [2, E] int32
    const int*   batch= (const int*)d_in[2];
    const float* w1l  = (const float*)d_in[3];
    const float* b1   = (const float*)d_in[4];
    const float* w1r  = (const float*)d_in[5];
    const float* w2l  = (const float*)d_in[6];
    const float* b2   = (const float*)d_in[7];
    const float* w2r  = (const float*)d_in[8];
    float* out = (float*)d_out;

    const int* src = ei;
    const int* dst = ei + NEDGES;

    int*   ws_i = (int*)d_ws;
    float* ws_f = (float*)d_ws;
    int*   gcnt = ws_i + OFF_GCNT;
    float* ginv = ws_f + OFF_GINV;
    int*   ebuf = ws_i + OFF_EBUF;
    float* xl   = ws_f + OFF_XL;
    float* xr   = ws_f + OFF_XR;
    float* h    = ws_f + OFF_H;

    hipMemsetAsync(gcnt, 0, 512 * sizeof(int), stream);
    hipMemsetAsync(out, 0, NGRAPH * COUT * sizeof(float), stream);

    binsort    <<<NTB, 512, 0, stream>>>(src, dst, gcnt, ebuf);
    transform1 <<<NBUCKET, 256, 0, stream>>>(x, w1l, b1, w1r, xl, xr);
    graph_inv  <<<1, 64, 0, stream>>>(batch, ginv);
    agg1_direct<<<NBUCKET, 512, 0, stream>>>(gcnt, ebuf, xl, xr, h);
    agg2_pool  <<<NBUCKET, 512, 0, stream>>>(gcnt, ebuf, h, w2l, b2, w2r, batch, ginv, out);
}

// Round 6
// 286.820 us; speedup vs baseline: 2.6641x; 2.6641x over previous
//
#include <hip/hip_runtime.h>
#include <hip/hip_bf16.h>

#define NNODES 100000
#define NEDGES 2500000
#define CIN 32
#define CHID 16
#define COUT 64
#define NGRAPH 64

#define NPB 256                 // nodes per bucket
#define NBUCKET 391             // ceil(100000/256)
#define BCAP 7424               // per-bucket capacity: mean 6394, sigma ~80 -> ~13 sigma
#define TILE 8192               // edges per binsort block
#define NTB 306                 // ceil(2.5M/8192)

// ---------------- workspace layout (4-byte units) ----------------------------
// gcnt  [0, 512)                int, zeroed (391 used)
// boff  [512, 1024)             int
// ginv  [1024, 1088)            f32
// offs  [1088, 101120)          int (100001 used)
// csr   [101120, 2601120)       int (src ids, dst-sorted)
// ebuf  [2601152, 5503936)      int packed (src<<8)|dst_local, 391*7424
// xl    [5503936, 7103936)      f32 N*16
// xr    [7103936, 8703936)      f32 N*16
// h     [8703936, 10303936)     f32 N*16   => 41.2 MB total
#define OFF_GCNT  0
#define OFF_BOFF  512
#define OFF_GINV  1024
#define OFF_OFFS  1088
#define OFF_CSR   101120
#define OFF_EBUF  2601152
#define OFF_XL    5503936
#define OFF_XR    7103936
#define OFF_H     8703936

// LDS counting-sort binning: each block sorts 8192 contiguous edges by
// 256-node bucket in LDS, then copies each bucket's run CONTIGUOUSLY into the
// bucket's global region (one space-claim atomic per non-empty bucket).
// Global writes are sequential full lines -> ~1x write amp (R5-proven fast).
__global__ __launch_bounds__(512) void binsort(const int* __restrict__ src,
                                               const int* __restrict__ dst,
                                               int* __restrict__ gcnt,
                                               int* __restrict__ ebuf) {
    __shared__ int hist[NBUCKET];
    __shared__ int binstart[NBUCKET];
    __shared__ int cursor[NBUCKET];
    __shared__ int gbase[NBUCKET];
    __shared__ int tmp[512];
    __shared__ int sbuf[TILE];
    int tid = threadIdx.x;
    int base = blockIdx.x * TILE;
    int cnt = min(NEDGES - base, TILE);
    for (int i = tid; i < NBUCKET; i += 512) hist[i] = 0;
    __syncthreads();
    int v[16], k[16];
#pragma unroll
    for (int j = 0; j < 16; j++) {
        int i = tid + j * 512;
        if (i < cnt) {
            int d = dst[base + i], s = src[base + i];
            k[j] = d >> 8;
            v[j] = (s << 8) | (d & 255);
            atomicAdd(&hist[k[j]], 1);
        }
    }
    __syncthreads();
    int hv = (tid < NBUCKET) ? hist[tid] : 0;
    tmp[tid] = hv;
    __syncthreads();
#pragma unroll
    for (int dd = 1; dd < 512; dd <<= 1) {
        int u = (tid >= dd) ? tmp[tid - dd] : 0;
        __syncthreads();
        tmp[tid] += u;
        __syncthreads();
    }
    if (tid < NBUCKET) {
        int excl = tmp[tid] - hv;
        binstart[tid] = excl;
        cursor[tid] = excl;
        gbase[tid] = (hv > 0) ? atomicAdd(&gcnt[tid], hv) : 0;
    }
    __syncthreads();
#pragma unroll
    for (int j = 0; j < 16; j++) {
        int i = tid + j * 512;
        if (i < cnt) {
            int p = atomicAdd(&cursor[k[j]], 1);
            sbuf[p] = v[j];
        }
    }
    __syncthreads();
    // wave w copies bins w, w+8, ...; run stores are contiguous
    int wave = tid >> 6, lane = tid & 63;
    for (int b = wave; b < NBUCKET; b += 8) {
        int c2 = hist[b];
        if (c2 == 0) continue;
        int g = gbase[b];
        int gs = min(g, BCAP);
        int ncopy = min(g + c2, BCAP) - gs;    // overflow-guarded (13 sigma)
        int ls = binstart[b];
        int* dp = ebuf + (size_t)b * BCAP + gs;
        for (int i = lane; i < ncopy; i += 64) dp[i] = sbuf[ls + i];
    }
}

// exclusive scan of the 391 bucket counts
__global__ __launch_bounds__(512) void scan_boff(const int* __restrict__ gcnt,
                                                 int* __restrict__ boff) {
    __shared__ int tmp[512];
    int t = threadIdx.x;
    int v = (t < NBUCKET) ? min(gcnt[t], BCAP) : 0;
    tmp[t] = v;
    __syncthreads();
#pragma unroll
    for (int d = 1; d < 512; d <<= 1) {
        int u = (t >= d) ? tmp[t - d] : 0;
        __syncthreads();
        tmp[t] += u;
        __syncthreads();
    }
    if (t < NBUCKET) boff[t] = tmp[t] - v;
}

// one block per bucket: counting-sort the bucket run into true CSR.
// All global writes land in a ~25KB window -> L2-resident, dense writeback
// (same pattern as R3/R4 bucket_build, which was cheap).
__global__ __launch_bounds__(256) void bucket_build(const int* __restrict__ gcnt,
                                                    const int* __restrict__ boff,
                                                    const int* __restrict__ ebuf,
                                                    int* __restrict__ csr,
                                                    int* __restrict__ offs) {
    __shared__ int hist[NPB];
    __shared__ int tmp[NPB];
    int b = blockIdx.x, tid = threadIdx.x;
    int nodes0 = b << 8;
    int nloc = min(NPB, NNODES - nodes0);
    int cnt = min(gcnt[b], BCAP);
    int base = boff[b];
    hist[tid] = 0;
    __syncthreads();
    const int* run = ebuf + (size_t)b * BCAP;
    for (int i = tid; i < cnt; i += 256) atomicAdd(&hist[run[i] & 255], 1);
    __syncthreads();
    tmp[tid] = hist[tid];
    __syncthreads();
#pragma unroll
    for (int d = 1; d < NPB; d <<= 1) {
        int u = (tid >= d) ? tmp[tid - d] : 0;
        __syncthreads();
        tmp[tid] += u;
        __syncthreads();
    }
    int excl = tmp[tid] - hist[tid];
    hist[tid] = excl;                      // becomes running cursor
    if (tid < nloc) offs[nodes0 + tid] = base + excl;
    if (b == NBUCKET - 1 && tid == NPB - 1) offs[NNODES] = base + tmp[NPB - 1];
    __syncthreads();
    for (int i = tid; i < cnt; i += 256) {
        int v = run[i];
        int p = atomicAdd(&hist[v & 255], 1);
        csr[base + p] = v >> 8;
    }
}

__device__ inline int lower_bound_i(const int* __restrict__ b, int n, int key) {
    int lo = 0, hi = n;
    while (lo < hi) {
        int m = (lo + hi) >> 1;
        if (b[m] < key) lo = m + 1; else hi = m;
    }
    return lo;
}

__global__ void graph_inv(const int* __restrict__ batch, float* __restrict__ ginv) {
    int g = threadIdx.x;
    if (g >= NGRAPH) return;
    int s = lower_bound_i(batch, NNODES, g);
    int e = lower_bound_i(batch, NNODES, g + 1);
    ginv[g] = 1.0f / (float)max(e - s, 1);
}

// xl = x @ w1_l.T ; xr = x @ w1_r.T + b1
__global__ __launch_bounds__(256) void transform1(const float* __restrict__ x,
                                                  const float* __restrict__ w1l,
                                                  const float* __restrict__ b1,
                                                  const float* __restrict__ w1r,
                                                  float* __restrict__ xl,
                                                  float* __restrict__ xr) {
    __shared__ float wl[CHID * CIN];
    __shared__ float wr[CHID * CIN];
    __shared__ float bs[CHID];
    for (int i = threadIdx.x; i < CHID * CIN; i += 256) { wl[i] = w1l[i]; wr[i] = w1r[i]; }
    if (threadIdx.x < CHID) bs[threadIdx.x] = b1[threadIdx.x];
    __syncthreads();
    int n = blockIdx.x * 256 + threadIdx.x;
    if (n >= NNODES) return;
    float xv[CIN];
    const float4* x4 = (const float4*)(x + (size_t)n * CIN);
#pragma unroll
    for (int q = 0; q < CIN / 4; q++) {
        float4 v = x4[q];
        xv[4*q] = v.x; xv[4*q+1] = v.y; xv[4*q+2] = v.z; xv[4*q+3] = v.w;
    }
#pragma unroll
    for (int o = 0; o < CHID; o++) {
        float aL = 0.f, aR = bs[o];
#pragma unroll
        for (int i = 0; i < CIN; i++) {
            aL = fmaf(wl[o * CIN + i], xv[i], aL);
            aR = fmaf(wr[o * CIN + i], xv[i], aR);
        }
        xl[(size_t)n * CHID + o] = aL;
        xr[(size_t)n * CHID + o] = aR;
    }
}

// layer-1 aggregate + finalize: h[n] = relu(mean_in(xl[src]) + xr[n])
// 16 lanes per node, lane c owns channel c; csr[p] broadcast-read, 64B
// coalesced gather per edge, NO atomics (R4-proven fast).
__global__ __launch_bounds__(256) void agg1_fused(const int* __restrict__ offs,
                                                  const int* __restrict__ csr,
                                                  const float* __restrict__ xl,
                                                  const float* __restrict__ xr,
                                                  float* __restrict__ h) {
    int node = blockIdx.x * 16 + (threadIdx.x >> 4);
    int c = threadIdx.x & 15;
    int s0 = offs[node], s1 = offs[node + 1];
    float a0 = 0.f, a1 = 0.f, a2 = 0.f, a3 = 0.f;
    int p = s0;
    for (; p + 3 < s1; p += 4) {
        int sA = csr[p], sB = csr[p + 1], sC = csr[p + 2], sD = csr[p + 3];
        a0 += xl[(size_t)sA * CHID + c];
        a1 += xl[(size_t)sB * CHID + c];
        a2 += xl[(size_t)sC * CHID + c];
        a3 += xl[(size_t)sD * CHID + c];
    }
    for (; p < s1; p++) a0 += xl[(size_t)csr[p] * CHID + c];
    float acc = (a0 + a1) + (a2 + a3);
    float mean = acc / (float)max(s1 - s0, 1);
    h[(size_t)node * CHID + c] = fmaxf(mean + xr[(size_t)node * CHID + c], 0.f);
}

// layer-2 aggregate + output transform + fused graph pooling
__global__ __launch_bounds__(256) void agg2_pool(const int* __restrict__ offs,
                                                 const int* __restrict__ csr,
                                                 const float* __restrict__ h,
                                                 const float* __restrict__ w2l,
                                                 const float* __restrict__ b2,
                                                 const float* __restrict__ w2r,
                                                 const int* __restrict__ batch,
                                                 const float* __restrict__ ginv,
                                                 float* __restrict__ out) {
    __shared__ float wlT[CHID * COUT];      // transposed: conflict-free
    __shared__ float wrT[CHID * COUT];
    __shared__ float bs[COUT];
    __shared__ float mean_s[16 * CHID];
    __shared__ float pool[16 * COUT];
    __shared__ int used[16];
    for (int idx = threadIdx.x; idx < CHID * COUT; idx += 256) {
        int i = idx >> 6, o = idx & 63;
        wlT[idx] = w2l[o * CHID + i];
        wrT[idx] = w2r[o * CHID + i];
    }
    if (threadIdx.x < COUT) bs[threadIdx.x] = b2[threadIdx.x];
    for (int idx = threadIdx.x; idx < 16 * COUT; idx += 256) pool[idx] = 0.f;
    if (threadIdx.x < 16) used[threadIdx.x] = 0;
    __syncthreads();

    int g = threadIdx.x >> 4;
    int c = threadIdx.x & 15;
    int node = blockIdx.x * 16 + g;         // grid exact: 6250*16 = 100000
    int gbase = batch[blockIdx.x * 16];     // sorted batch -> gloc in [0,16)
    int gid = batch[node];
    int gloc = gid - gbase;
    float gw = ginv[gid];
    if (c == 0) used[gloc] = 1;

    int s0 = offs[node], s1 = offs[node + 1];
    float a0 = 0.f, a1 = 0.f, a2 = 0.f, a3 = 0.f;
    int p = s0;
    for (; p + 3 < s1; p += 4) {
        int sA = csr[p], sB = csr[p + 1], sC = csr[p + 2], sD = csr[p + 3];
        a0 += h[(size_t)sA * CHID + c];
        a1 += h[(size_t)sB * CHID + c];
        a2 += h[(size_t)sC * CHID + c];
        a3 += h[(size_t)sD * CHID + c];
    }
    for (; p < s1; p++) a0 += h[(size_t)csr[p] * CHID + c];
    float acc = (a0 + a1) + (a2 + a3);
    mean_s[g * CHID + c] = acc / (float)max(s1 - s0, 1);
    __syncthreads();

    float hv[CHID], m[CHID];
    const float4* h4 = (const float4*)(h + (size_t)node * CHID);
#pragma unroll
    for (int q = 0; q < CHID / 4; q++) {
        float4 v = h4[q];
        hv[4*q] = v.x; hv[4*q+1] = v.y; hv[4*q+2] = v.z; hv[4*q+3] = v.w;
    }
#pragma unroll
    for (int i = 0; i < CHID; i++) m[i] = mean_s[g * CHID + i];

#pragma unroll
    for (int k = 0; k < 4; k++) {
        int o = c + 16 * k;
        float s = bs[o];
#pragma unroll
        for (int i = 0; i < CHID; i++) {
            s = fmaf(wlT[i * COUT + o], m[i], s);
            s = fmaf(wrT[i * COUT + o], hv[i], s);
        }
        atomicAdd(&pool[gloc * COUT + o], s * gw);
    }
    __syncthreads();
    for (int idx = threadIdx.x; idx < 16 * COUT; idx += 256) {
        int row = idx >> 6;
        if (used[row]) atomicAdd(&out[(gbase + row) * COUT + (idx & 63)], pool[idx]);
    }
}

extern "C" void kernel_launch(void* const* d_in, const int* in_sizes, int n_in,
                              void* d_out, int out_size, void* d_ws, size_t ws_size,
                              hipStream_t stream) {
    const float* x    = (const float*)d_in[0];
    const int*   ei   = (const int*)d_in[1];   // [2, E] int32
    const int*   batch= (const int*)d_in[2];
    const float* w1l  = (const float*)d_in[3];
    const float* b1   = (const float*)d_in[4];
    const float* w1r  = (const float*)d_in[5];
    const float* w2l  = (const float*)d_in[6];
    const float* b2   = (const float*)d_in[7];
    const float* w2r  = (const float*)d_in[8];
    float* out = (float*)d_out;

    const int* src = ei;
    const int* dst = ei + NEDGES;

    int*   ws_i = (int*)d_ws;
    float* ws_f = (float*)d_ws;
    int*   gcnt = ws_i + OFF_GCNT;
    int*   boff = ws_i + OFF_BOFF;
    float* ginv = ws_f + OFF_GINV;
    int*   offs = ws_i + OFF_OFFS;
    int*   csr  = ws_i + OFF_CSR;
    int*   ebuf = ws_i + OFF_EBUF;
    float* xl   = ws_f + OFF_XL;
    float* xr   = ws_f + OFF_XR;
    float* h    = ws_f + OFF_H;

    hipMemsetAsync(gcnt, 0, 512 * sizeof(int), stream);
    hipMemsetAsync(out, 0, NGRAPH * COUT * sizeof(float), stream);

    int nbl = (NNODES + 255) / 256;   // 391
    int abl = NNODES / 16;            // 6250, exact

    binsort     <<<NTB, 512, 0, stream>>>(src, dst, gcnt, ebuf);
    transform1  <<<nbl, 256, 0, stream>>>(x, w1l, b1, w1r, xl, xr);
    graph_inv   <<<1, 64, 0, stream>>>(batch, ginv);
    scan_boff   <<<1, 512, 0, stream>>>(gcnt, boff);
    bucket_build<<<NBUCKET, 256, 0, stream>>>(gcnt, boff, ebuf, csr, offs);
    agg1_fused  <<<abl, 256, 0, stream>>>(offs, csr, xl, xr, h);
    agg2_pool   <<<abl, 256, 0, stream>>>(offs, csr, h, w2l, b2, w2r, batch, ginv, out);
}

// Round 7
// 269.971 us; speedup vs baseline: 2.8304x; 1.0624x over previous
//
#include <hip/hip_runtime.h>
#include <hip/hip_bf16.h>
#include <hip/hip_fp16.h>

#define NNODES 100000
#define NEDGES 2500000
#define CIN 32
#define CHID 16
#define COUT 64
#define NGRAPH 64

#define NPB 256                 // nodes per bucket
#define NBUCKET 391             // ceil(100000/256)
#define BCAP 7424               // per-bucket capacity: mean 6394, sigma ~80 -> ~13 sigma
#define TILE 8192               // edges per binsort block
#define NTB 306                 // ceil(2.5M/8192)

// ---------------- workspace layout (4-byte units) ----------------------------
// gcnt  [0, 512)                int, zeroed (391 used)
// boff  [512, 1024)             int
// ginv  [1024, 1088)            f32
// offs  [1088, 101120)          int (100001 used)
// csr   [101152, 2601152)      int (src ids, dst-sorted)
// ebuf  [2601152, 5503936)      int packed (src<<8)|dst_local
// xlh   [5503936, 6303936)      f16 N*16 (3.2MB -> per-XCD L2-resident)
// xr    [6303936, 7903936)      f32 N*16
// hh    [7903936, 8703936)      f16 N*16   => 34.8 MB total
#define OFF_GCNT  0
#define OFF_BOFF  512
#define OFF_GINV  1024
#define OFF_OFFS  1088
#define OFF_CSR   101152
#define OFF_EBUF  2601152
#define OFF_XLH   5503936
#define OFF_XR    6303936
#define OFF_HH    7903936

// LDS counting-sort binning (R5/R6-proven): dense sequential bucket-run writes
__global__ __launch_bounds__(512) void binsort(const int* __restrict__ src,
                                               const int* __restrict__ dst,
                                               int* __restrict__ gcnt,
                                               int* __restrict__ ebuf) {
    __shared__ int hist[NBUCKET];
    __shared__ int binstart[NBUCKET];
    __shared__ int cursor[NBUCKET];
    __shared__ int gbase[NBUCKET];
    __shared__ int tmp[512];
    __shared__ int sbuf[TILE];
    int tid = threadIdx.x;
    int base = blockIdx.x * TILE;
    int cnt = min(NEDGES - base, TILE);
    for (int i = tid; i < NBUCKET; i += 512) hist[i] = 0;
    __syncthreads();
    int v[16], k[16];
#pragma unroll
    for (int j = 0; j < 16; j++) {
        int i = tid + j * 512;
        if (i < cnt) {
            int d = dst[base + i], s = src[base + i];
            k[j] = d >> 8;
            v[j] = (s << 8) | (d & 255);
            atomicAdd(&hist[k[j]], 1);
        }
    }
    __syncthreads();
    int hv = (tid < NBUCKET) ? hist[tid] : 0;
    tmp[tid] = hv;
    __syncthreads();
#pragma unroll
    for (int dd = 1; dd < 512; dd <<= 1) {
        int u = (tid >= dd) ? tmp[tid - dd] : 0;
        __syncthreads();
        tmp[tid] += u;
        __syncthreads();
    }
    if (tid < NBUCKET) {
        int excl = tmp[tid] - hv;
        binstart[tid] = excl;
        cursor[tid] = excl;
        gbase[tid] = (hv > 0) ? atomicAdd(&gcnt[tid], hv) : 0;
    }
    __syncthreads();
#pragma unroll
    for (int j = 0; j < 16; j++) {
        int i = tid + j * 512;
        if (i < cnt) {
            int p = atomicAdd(&cursor[k[j]], 1);
            sbuf[p] = v[j];
        }
    }
    __syncthreads();
    int wave = tid >> 6, lane = tid & 63;
    for (int b = wave; b < NBUCKET; b += 8) {
        int c2 = hist[b];
        if (c2 == 0) continue;
        int g = gbase[b];
        int gs = min(g, BCAP);
        int ncopy = min(g + c2, BCAP) - gs;    // overflow-guarded
        int ls = binstart[b];
        int* dp = ebuf + (size_t)b * BCAP + gs;
        for (int i = lane; i < ncopy; i += 64) dp[i] = sbuf[ls + i];
    }
}

__device__ inline int lower_bound_i(const int* __restrict__ b, int n, int key) {
    int lo = 0, hi = n;
    while (lo < hi) {
        int m = (lo + hi) >> 1;
        if (b[m] < key) lo = m + 1; else hi = m;
    }
    return lo;
}

// block 0: exclusive scan of bucket counts; block 1: per-graph 1/count
__global__ __launch_bounds__(512) void scan_and_ginv(const int* __restrict__ gcnt,
                                                     int* __restrict__ boff,
                                                     const int* __restrict__ batch,
                                                     float* __restrict__ ginv) {
    int t = threadIdx.x;
    if (blockIdx.x == 1) {
        if (t < NGRAPH) {
            int s = lower_bound_i(batch, NNODES, t);
            int e = lower_bound_i(batch, NNODES, t + 1);
            ginv[t] = 1.0f / (float)max(e - s, 1);
        }
        return;
    }
    __shared__ int tmp[512];
    int v = (t < NBUCKET) ? min(gcnt[t], BCAP) : 0;
    tmp[t] = v;
    __syncthreads();
#pragma unroll
    for (int d = 1; d < 512; d <<= 1) {
        int u = (t >= d) ? tmp[t - d] : 0;
        __syncthreads();
        tmp[t] += u;
        __syncthreads();
    }
    if (t < NBUCKET) boff[t] = tmp[t] - v;
}

// counting-sort each bucket run into true CSR (writes confined to ~25KB window)
__global__ __launch_bounds__(256) void bucket_build(const int* __restrict__ gcnt,
                                                    const int* __restrict__ boff,
                                                    const int* __restrict__ ebuf,
                                                    int* __restrict__ csr,
                                                    int* __restrict__ offs) {
    __shared__ int hist[NPB];
    __shared__ int tmp[NPB];
    int b = blockIdx.x, tid = threadIdx.x;
    int nodes0 = b << 8;
    int nloc = min(NPB, NNODES - nodes0);
    int cnt = min(gcnt[b], BCAP);
    int base = boff[b];
    hist[tid] = 0;
    __syncthreads();
    const int* run = ebuf + (size_t)b * BCAP;
    for (int i = tid; i < cnt; i += 256) atomicAdd(&hist[run[i] & 255], 1);
    __syncthreads();
    tmp[tid] = hist[tid];
    __syncthreads();
#pragma unroll
    for (int d = 1; d < NPB; d <<= 1) {
        int u = (tid >= d) ? tmp[tid - d] : 0;
        __syncthreads();
        tmp[tid] += u;
        __syncthreads();
    }
    int excl = tmp[tid] - hist[tid];
    hist[tid] = excl;
    if (tid < nloc) offs[nodes0 + tid] = base + excl;
    if (b == NBUCKET - 1 && tid == NPB - 1) offs[NNODES] = base + tmp[NPB - 1];
    __syncthreads();
    for (int i = tid; i < cnt; i += 256) {
        int v = run[i];
        int p = atomicAdd(&hist[v & 255], 1);
        csr[base + p] = v >> 8;
    }
}

// xl(f16) = x @ w1_l.T ; xr(f32) = x @ w1_r.T + b1
__global__ __launch_bounds__(256) void transform1(const float* __restrict__ x,
                                                  const float* __restrict__ w1l,
                                                  const float* __restrict__ b1,
                                                  const float* __restrict__ w1r,
                                                  __half* __restrict__ xlh,
                                                  float* __restrict__ xr) {
    __shared__ float wl[CHID * CIN];
    __shared__ float wr[CHID * CIN];
    __shared__ float bs[CHID];
    for (int i = threadIdx.x; i < CHID * CIN; i += 256) { wl[i] = w1l[i]; wr[i] = w1r[i]; }
    if (threadIdx.x < CHID) bs[threadIdx.x] = b1[threadIdx.x];
    __syncthreads();
    int n = blockIdx.x * 256 + threadIdx.x;
    if (n >= NNODES) return;
    float xv[CIN];
    const float4* x4 = (const float4*)(x + (size_t)n * CIN);
#pragma unroll
    for (int q = 0; q < CIN / 4; q++) {
        float4 v = x4[q];
        xv[4*q] = v.x; xv[4*q+1] = v.y; xv[4*q+2] = v.z; xv[4*q+3] = v.w;
    }
    float oL[CHID];
#pragma unroll
    for (int o = 0; o < CHID; o++) {
        float aL = 0.f, aR = bs[o];
#pragma unroll
        for (int i = 0; i < CIN; i++) {
            aL = fmaf(wl[o * CIN + i], xv[i], aL);
            aR = fmaf(wr[o * CIN + i], xv[i], aR);
        }
        oL[o] = aL;
        xr[(size_t)n * CHID + o] = aR;
    }
    __half2* xp = (__half2*)(xlh + (size_t)n * CHID);
#pragma unroll
    for (int q = 0; q < CHID / 2; q++)
        xp[q] = __floats2half2_rn(oL[2*q], oL[2*q+1]);
}

// layer-1 aggregate + finalize: h(f16) = relu(mean_in(xl[src]) + xr)
// 16 lanes per node; f16 gathers (3.2MB array -> per-XCD L2-resident); unroll 8
__global__ __launch_bounds__(256) void agg1_fused(const int* __restrict__ offs,
                                                  const int* __restrict__ csr,
                                                  const __half* __restrict__ xlh,
                                                  const float* __restrict__ xr,
                                                  __half* __restrict__ hh) {
    int node = blockIdx.x * 16 + (threadIdx.x >> 4);
    int c = threadIdx.x & 15;
    int s0 = offs[node], s1 = offs[node + 1];
    float a0 = 0.f, a1 = 0.f, a2 = 0.f, a3 = 0.f;
    float a4 = 0.f, a5 = 0.f, a6 = 0.f, a7 = 0.f;
    int p = s0;
    for (; p + 7 < s1; p += 8) {
        int sA = csr[p],     sB = csr[p + 1], sC = csr[p + 2], sD = csr[p + 3];
        int sE = csr[p + 4], sF = csr[p + 5], sG = csr[p + 6], sH = csr[p + 7];
        a0 += __half2float(xlh[(size_t)sA * CHID + c]);
        a1 += __half2float(xlh[(size_t)sB * CHID + c]);
        a2 += __half2float(xlh[(size_t)sC * CHID + c]);
        a3 += __half2float(xlh[(size_t)sD * CHID + c]);
        a4 += __half2float(xlh[(size_t)sE * CHID + c]);
        a5 += __half2float(xlh[(size_t)sF * CHID + c]);
        a6 += __half2float(xlh[(size_t)sG * CHID + c]);
        a7 += __half2float(xlh[(size_t)sH * CHID + c]);
    }
    for (; p < s1; p++) a0 += __half2float(xlh[(size_t)csr[p] * CHID + c]);
    float acc = ((a0 + a1) + (a2 + a3)) + ((a4 + a5) + (a6 + a7));
    float mean = acc / (float)max(s1 - s0, 1);
    float hval = fmaxf(mean + xr[(size_t)node * CHID + c], 0.f);
    hh[(size_t)node * CHID + c] = __float2half(hval);
}

// layer-2 aggregate + output transform + fused graph pooling
__global__ __launch_bounds__(256) void agg2_pool(const int* __restrict__ offs,
                                                 const int* __restrict__ csr,
                                                 const __half* __restrict__ hh,
                                                 const float* __restrict__ w2l,
                                                 const float* __restrict__ b2,
                                                 const float* __restrict__ w2r,
                                                 const int* __restrict__ batch,
                                                 const float* __restrict__ ginv,
                                                 float* __restrict__ out) {
    __shared__ float wlT[CHID * COUT];      // transposed: conflict-free
    __shared__ float wrT[CHID * COUT];
    __shared__ float bs[COUT];
    __shared__ float mean_s[16 * CHID];
    __shared__ float pool[16 * COUT];
    __shared__ int used[16];
    for (int idx = threadIdx.x; idx < CHID * COUT; idx += 256) {
        int i = idx >> 6, o = idx & 63;
        wlT[idx] = w2l[o * CHID + i];
        wrT[idx] = w2r[o * CHID + i];
    }
    if (threadIdx.x < COUT) bs[threadIdx.x] = b2[threadIdx.x];
    for (int idx = threadIdx.x; idx < 16 * COUT; idx += 256) pool[idx] = 0.f;
    if (threadIdx.x < 16) used[threadIdx.x] = 0;
    __syncthreads();

    int g = threadIdx.x >> 4;
    int c = threadIdx.x & 15;
    int node = blockIdx.x * 16 + g;         // grid exact: 6250*16 = 100000
    int gbase = batch[blockIdx.x * 16];
    int gid = batch[node];
    int gloc = gid - gbase;
    float gw = ginv[gid];
    if (c == 0) used[gloc] = 1;

    int s0 = offs[node], s1 = offs[node + 1];
    float a0 = 0.f, a1 = 0.f, a2 = 0.f, a3 = 0.f;
    float a4 = 0.f, a5 = 0.f, a6 = 0.f, a7 = 0.f;
    int p = s0;
    for (; p + 7 < s1; p += 8) {
        int sA = csr[p],     sB = csr[p + 1], sC = csr[p + 2], sD = csr[p + 3];
        int sE = csr[p + 4], sF = csr[p + 5], sG = csr[p + 6], sH = csr[p + 7];
        a0 += __half2float(hh[(size_t)sA * CHID + c]);
        a1 += __half2float(hh[(size_t)sB * CHID + c]);
        a2 += __half2float(hh[(size_t)sC * CHID + c]);
        a3 += __half2float(hh[(size_t)sD * CHID + c]);
        a4 += __half2float(hh[(size_t)sE * CHID + c]);
        a5 += __half2float(hh[(size_t)sF * CHID + c]);
        a6 += __half2float(hh[(size_t)sG * CHID + c]);
        a7 += __half2float(hh[(size_t)sH * CHID + c]);
    }
    for (; p < s1; p++) a0 += __half2float(hh[(size_t)csr[p] * CHID + c]);
    float acc = ((a0 + a1) + (a2 + a3)) + ((a4 + a5) + (a6 + a7));
    mean_s[g * CHID + c] = acc / (float)max(s1 - s0, 1);
    __syncthreads();

    float hv[CHID], m[CHID];
    const __half2* h2p = (const __half2*)(hh + (size_t)node * CHID);
#pragma unroll
    for (int q = 0; q < CHID / 2; q++) {
        float2 f = __half22float2(h2p[q]);
        hv[2*q] = f.x; hv[2*q+1] = f.y;
    }
#pragma unroll
    for (int i = 0; i < CHID; i++) m[i] = mean_s[g * CHID + i];

#pragma unroll
    for (int k = 0; k < 4; k++) {
        int o = c + 16 * k;
        float s = bs[o];
#pragma unroll
        for (int i = 0; i < CHID; i++) {
            s = fmaf(wlT[i * COUT + o], m[i], s);
            s = fmaf(wrT[i * COUT + o], hv[i], s);
        }
        atomicAdd(&pool[gloc * COUT + o], s * gw);
    }
    __syncthreads();
    for (int idx = threadIdx.x; idx < 16 * COUT; idx += 256) {
        int row = idx >> 6;
        if (used[row]) atomicAdd(&out[(gbase + row) * COUT + (idx & 63)], pool[idx]);
    }
}

extern "C" void kernel_launch(void* const* d_in, const int* in_sizes, int n_in,
                              void* d_out, int out_size, void* d_ws, size_t ws_size,
                              hipStream_t stream) {
    const float* x    = (const float*)d_in[0];
    const int*   ei   = (const int*)d_in[1];   // [2, E] int32
    const int*   batch= (const int*)d_in[2];
    const float* w1l  = (const float*)d_in[3];
    const float* b1   = (const float*)d_in[4];
    const float* w1r  = (const float*)d_in[5];
    const float* w2l  = (const float*)d_in[6];
    const float* b2   = (const float*)d_in[7];
    const float* w2r  = (const float*)d_in[8];
    float* out = (float*)d_out;

    const int* src = ei;
    const int* dst = ei + NEDGES;

    int*    ws_i = (int*)d_ws;
    float*  ws_f = (float*)d_ws;
    int*    gcnt = ws_i + OFF_GCNT;
    int*    boff = ws_i + OFF_BOFF;
    float*  ginv = ws_f + OFF_GINV;
    int*    offs = ws_i + OFF_OFFS;
    int*    csr  = ws_i + OFF_CSR;
    int*    ebuf = ws_i + OFF_EBUF;
    __half* xlh  = (__half*)(ws_i + OFF_XLH);
    float*  xr   = ws_f + OFF_XR;
    __half* hh   = (__half*)(ws_i + OFF_HH);

    hipMemsetAsync(gcnt, 0, 512 * sizeof(int), stream);
    hipMemsetAsync(out, 0, NGRAPH * COUT * sizeof(float), stream);

    int nbl = (NNODES + 255) / 256;   // 391
    int abl = NNODES / 16;            // 6250, exact

    binsort      <<<NTB, 512, 0, stream>>>(src, dst, gcnt, ebuf);
    transform1   <<<nbl, 256, 0, stream>>>(x, w1l, b1, w1r, xlh, xr);
    scan_and_ginv<<<2, 512, 0, stream>>>(gcnt, boff, batch, ginv);
    bucket_build <<<NBUCKET, 256, 0, stream>>>(gcnt, boff, ebuf, csr, offs);
    agg1_fused   <<<abl, 256, 0, stream>>>(offs, csr, xlh, xr, hh);
    agg2_pool    <<<abl, 256, 0, stream>>>(offs, csr, hh, w2l, b2, w2r, batch, ginv, out);
}